// Round 1
// baseline (386.716 us; speedup 1.0000x reference)
//
#include <hip/hip_runtime.h>

#define DIM 64

// ---------------- ws layout ----------------
// [0, 4)                : int flag (1 => edge_index stored as int64)
// [256, 256+4N)         : float deg[N]  (transformed in-place to dinv)
// [align256 after deg)  : float h[N*64]
// total ~ 26 MB

// Detect whether edge_index buffer is int64 (odd int32 words all zero) or int32.
__global__ void detect_idx64_kernel(const int* __restrict__ ei32, int* __restrict__ flag) {
    __shared__ int any_nz;
    if (threadIdx.x == 0) any_nz = 0;
    __syncthreads();
    int v = ei32[2 * threadIdx.x + 1];   // odd int32 positions, within bounds for both dtypes
    if (v != 0) atomicOr(&any_nz, 1);
    __syncthreads();
    if (threadIdx.x == 0) *flag = (any_nz == 0) ? 1 : 0;
}

__global__ void init_deg_kernel(float* __restrict__ deg, int N) {
    int i = blockIdx.x * blockDim.x + threadIdx.x;
    if (i < N) deg[i] = 1.0f;            // self-loop contribution
}

__global__ void count_deg_kernel(const void* __restrict__ ei, const int* __restrict__ flagp,
                                 float* __restrict__ deg, int E) {
    int is64 = *flagp;
    int stride = gridDim.x * blockDim.x;
    for (int i = blockIdx.x * blockDim.x + threadIdx.x; i < E; i += stride) {
        int d = is64 ? (int)((const long long*)ei)[(long long)i + E]
                     : ((const int*)ei)[i + E];
        unsafeAtomicAdd(&deg[d], 1.0f);
    }
}

__global__ void deg_to_dinv_kernel(float* __restrict__ deg, int N) {
    int i = blockIdx.x * blockDim.x + threadIdx.x;
    if (i < N) deg[i] = rsqrtf(deg[i]);  // deg >= 1 always (self-loop)
}

// h = x @ W^T.  Wave-per-row, lane-per-col. W row for lane's col kept in 64 regs.
__global__ __launch_bounds__(256) void gemm_kernel(const float* __restrict__ x,
                                                   const float* __restrict__ W,
                                                   float* __restrict__ h, int N) {
    __shared__ float Wt[64 * 64];        // k-major: Wt[k*64 + c] = W[c*64 + k]
    int tid = threadIdx.x;
    // dest-indexed staging: conflict-free LDS stores, strided (but tiny, cached) global reads
    for (int i = tid; i < 64 * 64; i += 256) {
        Wt[i] = W[((i & 63) << 6) | (i >> 6)];
    }
    __syncthreads();
    int lane = tid & 63;
    float wreg[64];
#pragma unroll
    for (int k = 0; k < 64; ++k) wreg[k] = Wt[k * 64 + lane];  // lanes consecutive: conflict-free

    int wave = (blockIdx.x * blockDim.x + threadIdx.x) >> 6;
    int nwaves = (gridDim.x * blockDim.x) >> 6;
    for (int r = wave; r < N; r += nwaves) {
        int rs = __builtin_amdgcn_readfirstlane(r);
        const float4* xr = (const float4*)(x + (long long)rs * DIM);  // wave-uniform address
        float acc = 0.0f;
#pragma unroll
        for (int kk = 0; kk < 16; ++kk) {
            float4 xv = xr[kk];
            acc = fmaf(xv.x, wreg[4 * kk + 0], acc);
            acc = fmaf(xv.y, wreg[4 * kk + 1], acc);
            acc = fmaf(xv.z, wreg[4 * kk + 2], acc);
            acc = fmaf(xv.w, wreg[4 * kk + 3], acc);
        }
        h[(long long)rs * DIM + lane] = acc;
    }
}

// out[i][f] = h[i][f] * dinv[i]^2 + b[f]   (self-loop term + bias)
__global__ void out_init_kernel(const float* __restrict__ h, const float* __restrict__ dinv,
                                const float* __restrict__ b, float* __restrict__ out, int N) {
    long long total = (long long)N * DIM;
    long long stride = (long long)gridDim.x * blockDim.x;
    for (long long i = (long long)blockIdx.x * blockDim.x + threadIdx.x; i < total; i += stride) {
        int node = (int)(i >> 6);
        int f = (int)(i & 63);
        float di = dinv[node];
        out[i] = h[i] * di * di + b[f];
    }
}

// wave-per-edge scatter: lane f does out[dst][f] += h[src][f] * dinv[src]*dinv[dst]
__global__ __launch_bounds__(256) void scatter_kernel(const void* __restrict__ ei,
                                                      const int* __restrict__ flagp,
                                                      const float* __restrict__ h,
                                                      const float* __restrict__ dinv,
                                                      float* __restrict__ out, int E) {
    int is64 = *flagp;
    int lane = threadIdx.x & 63;
    int wave = (blockIdx.x * blockDim.x + threadIdx.x) >> 6;
    int nw = (gridDim.x * blockDim.x) >> 6;
    for (int e = wave; e < E; e += nw) {
        int es = __builtin_amdgcn_readfirstlane(e);
        int s, d;
        if (is64) {
            s = (int)((const long long*)ei)[es];
            d = (int)((const long long*)ei)[(long long)es + E];
        } else {
            s = ((const int*)ei)[es];
            d = ((const int*)ei)[es + E];
        }
        float norm = dinv[s] * dinv[d];
        float val = h[(long long)s * DIM + lane] * norm;
        unsafeAtomicAdd(&out[(long long)d * DIM + lane], val);
    }
}

extern "C" void kernel_launch(void* const* d_in, const int* in_sizes, int n_in,
                              void* d_out, int out_size, void* d_ws, size_t ws_size,
                              hipStream_t stream) {
    const float* x = (const float*)d_in[0];
    const void* ei = d_in[1];
    const float* W = (const float*)d_in[2];
    const float* b = (const float*)d_in[3];
    float* out = (float*)d_out;

    int N = in_sizes[0] / DIM;   // 100000
    int E = in_sizes[1] / 2;     // 1000000

    char* ws = (char*)d_ws;
    int* flag = (int*)ws;
    float* deg = (float*)(ws + 256);                       // becomes dinv in-place
    size_t deg_bytes = ((size_t)N * 4 + 255) & ~(size_t)255;
    float* h = (float*)(ws + 256 + deg_bytes);             // N*64 floats

    detect_idx64_kernel<<<1, 256, 0, stream>>>((const int*)ei, flag);
    init_deg_kernel<<<(N + 255) / 256, 256, 0, stream>>>(deg, N);
    count_deg_kernel<<<1024, 256, 0, stream>>>(ei, flag, deg, E);
    deg_to_dinv_kernel<<<(N + 255) / 256, 256, 0, stream>>>(deg, N);
    gemm_kernel<<<1024, 256, 0, stream>>>(x, W, h, N);
    out_init_kernel<<<2048, 256, 0, stream>>>(h, deg, b, out, N);
    scatter_kernel<<<4096, 256, 0, stream>>>(ei, flag, h, deg, out, E);
}

// Round 2
// 299.339 us; speedup vs baseline: 1.2919x; 1.2919x over previous
//
#include <hip/hip_runtime.h>

#define DIM 64
#define SCAN_CHUNK 1024   // elements per scan block (256 thr x 4)

// ---------------- ws layout (all 256-aligned) ----------------
// flag(int) | counts[N] int | offsets[N] int | bsums[1024] int | dinv[N] f32
// | srcs[E] int | h[N*64] f32     (~31 MB total)

__global__ void detect_idx64_kernel(const int* __restrict__ ei32, int* __restrict__ flag) {
    __shared__ int any_nz;
    if (threadIdx.x == 0) any_nz = 0;
    __syncthreads();
    int v = ei32[2 * threadIdx.x + 1];   // odd int32 words: all-zero iff data is nonneg int64
    if (v != 0) atomicOr(&any_nz, 1);
    __syncthreads();
    if (threadIdx.x == 0) *flag = (any_nz == 0) ? 1 : 0;
}

__global__ void zero_counts_kernel(int* __restrict__ counts, int N) {
    int i = blockIdx.x * blockDim.x + threadIdx.x;
    if (i < N) counts[i] = 0;
}

__global__ void count_kernel(const void* __restrict__ ei, const int* __restrict__ flagp,
                             int* __restrict__ counts, int E) {
    int i = blockIdx.x * blockDim.x + threadIdx.x;
    if (i >= E) return;
    int is64 = *flagp;
    int d = is64 ? (int)((const long long*)ei)[(long long)i + E]
                 : ((const int*)ei)[i + E];
    atomicAdd(&counts[d], 1);
}

// phase 1: per-block sums of SCAN_CHUNK counts
__global__ __launch_bounds__(256) void scan_sums_kernel(const int* __restrict__ counts,
                                                        int* __restrict__ bsums, int N) {
    int t = threadIdx.x;
    int base = blockIdx.x * SCAN_CHUNK + t * 4;
    int s = 0;
#pragma unroll
    for (int k = 0; k < 4; ++k) { int i = base + k; if (i < N) s += counts[i]; }
    __shared__ int tmp[256];
    tmp[t] = s; __syncthreads();
    for (int off = 128; off > 0; off >>= 1) {
        if (t < off) tmp[t] += tmp[t + off];
        __syncthreads();
    }
    if (t == 0) bsums[blockIdx.x] = tmp[0];
}

// phase 2: single-block exclusive scan of block sums (NB <= 1024)
__global__ __launch_bounds__(1024) void scan_bsums_kernel(int* __restrict__ bsums, int NB) {
    __shared__ int tmp[1024];
    int t = threadIdx.x;
    int v = (t < NB) ? bsums[t] : 0;
    tmp[t] = v; __syncthreads();
    for (int off = 1; off < 1024; off <<= 1) {
        int u = (t >= off) ? tmp[t - off] : 0;
        __syncthreads();
        tmp[t] += u;
        __syncthreads();
    }
    if (t < NB) bsums[t] = tmp[t] - v;   // exclusive
}

// phase 3: per-element exclusive scan + base; also emits dinv = rsqrt(deg+1)
__global__ __launch_bounds__(256) void scan_write_kernel(const int* __restrict__ counts,
                                                         const int* __restrict__ bsums,
                                                         int* __restrict__ offsets,
                                                         float* __restrict__ dinv, int N) {
    int t = threadIdx.x;
    int base = blockIdx.x * SCAN_CHUNK + t * 4;
    int c[4]; int s = 0;
#pragma unroll
    for (int k = 0; k < 4; ++k) { int i = base + k; c[k] = (i < N) ? counts[i] : 0; s += c[k]; }
    __shared__ int tmp[256];
    tmp[t] = s; __syncthreads();
    for (int off = 1; off < 256; off <<= 1) {
        int u = (t >= off) ? tmp[t - off] : 0;
        __syncthreads();
        tmp[t] += u;
        __syncthreads();
    }
    int excl = tmp[t] - s + bsums[blockIdx.x];
#pragma unroll
    for (int k = 0; k < 4; ++k) {
        int i = base + k;
        if (i < N) {
            offsets[i] = excl; excl += c[k];
            dinv[i] = rsqrtf((float)(c[k] + 1));   // +1 self-loop; always > 0
        }
    }
}

// reorder: scatter src ids into dst-sorted order; offsets[] consumed -> inclusive sums
__global__ void reorder_kernel(const void* __restrict__ ei, const int* __restrict__ flagp,
                               int* __restrict__ offsets, int* __restrict__ srcs, int E) {
    int i = blockIdx.x * blockDim.x + threadIdx.x;
    if (i >= E) return;
    int is64 = *flagp;
    int s, d;
    if (is64) {
        s = (int)((const long long*)ei)[i];
        d = (int)((const long long*)ei)[(long long)i + E];
    } else {
        s = ((const int*)ei)[i];
        d = ((const int*)ei)[i + E];
    }
    int pos = atomicAdd(&offsets[d], 1);
    srcs[pos] = s;
}

// h = x @ W^T.  Wave-per-row, lane-per-col.
__global__ __launch_bounds__(256) void gemm_kernel(const float* __restrict__ x,
                                                   const float* __restrict__ W,
                                                   float* __restrict__ h, int N) {
    __shared__ float Wt[64 * 64];        // k-major
    int tid = threadIdx.x;
    for (int i = tid; i < 64 * 64; i += 256) Wt[i] = W[((i & 63) << 6) | (i >> 6)];
    __syncthreads();
    int lane = tid & 63;
    float wreg[64];
#pragma unroll
    for (int k = 0; k < 64; ++k) wreg[k] = Wt[k * 64 + lane];

    int wave = (blockIdx.x * blockDim.x + threadIdx.x) >> 6;
    int nwaves = (gridDim.x * blockDim.x) >> 6;
    for (int r = wave; r < N; r += nwaves) {
        int rs = __builtin_amdgcn_readfirstlane(r);
        const float4* xr = (const float4*)(x + (long long)rs * DIM);
        float acc = 0.0f;
#pragma unroll
        for (int kk = 0; kk < 16; ++kk) {
            float4 xv = xr[kk];
            acc = fmaf(xv.x, wreg[4 * kk + 0], acc);
            acc = fmaf(xv.y, wreg[4 * kk + 1], acc);
            acc = fmaf(xv.z, wreg[4 * kk + 2], acc);
            acc = fmaf(xv.w, wreg[4 * kk + 3], acc);
        }
        h[(long long)rs * DIM + lane] = acc;
    }
}

// wave-per-node segmented gather. After reorder, offsets[d] = inclusive sum:
// segment(d) = [d ? offsets[d-1] : 0, offsets[d]).  Self-loop + bias fused.
__global__ __launch_bounds__(256) void gather_kernel(const float* __restrict__ h,
                                                     const int* __restrict__ offsets,
                                                     const int* __restrict__ srcs,
                                                     const float* __restrict__ dinv,
                                                     const float* __restrict__ b,
                                                     float* __restrict__ out, int N) {
    int wave = (blockIdx.x * blockDim.x + threadIdx.x) >> 6;
    int lane = threadIdx.x & 63;
    if (wave >= N) return;
    int node = wave;
    int start = (node == 0) ? 0 : offsets[node - 1];
    int end = offsets[node];
    float dn = dinv[node];
    float acc = h[(long long)node * DIM + lane] * dn * dn;   // self-loop term
    int j = start;
    for (; j + 1 < end; j += 2) {
        int s0 = srcs[j], s1 = srcs[j + 1];
        float w0 = dinv[s0] * dn, w1 = dinv[s1] * dn;
        float v0 = h[(long long)s0 * DIM + lane];
        float v1 = h[(long long)s1 * DIM + lane];
        acc = fmaf(v0, w0, acc);
        acc = fmaf(v1, w1, acc);
    }
    if (j < end) {
        int s0 = srcs[j];
        acc = fmaf(h[(long long)s0 * DIM + lane], dinv[s0] * dn, acc);
    }
    out[(long long)node * DIM + lane] = acc + b[lane];
}

extern "C" void kernel_launch(void* const* d_in, const int* in_sizes, int n_in,
                              void* d_out, int out_size, void* d_ws, size_t ws_size,
                              hipStream_t stream) {
    const float* x = (const float*)d_in[0];
    const void* ei = d_in[1];
    const float* W = (const float*)d_in[2];
    const float* b = (const float*)d_in[3];
    float* out = (float*)d_out;

    int N = in_sizes[0] / DIM;   // 100000
    int E = in_sizes[1] / 2;     // 1000000

    char* ws = (char*)d_ws;
    auto align256 = [](size_t v) { return (v + 255) & ~(size_t)255; };
    size_t off = 0;
    int* flag = (int*)(ws + off);            off = align256(off + 4);
    int* counts = (int*)(ws + off);          off = align256(off + (size_t)N * 4);
    int* offsets = (int*)(ws + off);         off = align256(off + (size_t)N * 4);
    int* bsums = (int*)(ws + off);           off = align256(off + 1024 * 4);
    float* dinv = (float*)(ws + off);        off = align256(off + (size_t)N * 4);
    int* srcs = (int*)(ws + off);            off = align256(off + (size_t)E * 4);
    float* h = (float*)(ws + off);           off = align256(off + (size_t)N * DIM * 4);

    int NB = (N + SCAN_CHUNK - 1) / SCAN_CHUNK;   // 98

    detect_idx64_kernel<<<1, 256, 0, stream>>>((const int*)ei, flag);
    zero_counts_kernel<<<(N + 255) / 256, 256, 0, stream>>>(counts, N);
    count_kernel<<<(E + 255) / 256, 256, 0, stream>>>(ei, flag, counts, E);
    scan_sums_kernel<<<NB, 256, 0, stream>>>(counts, bsums, N);
    scan_bsums_kernel<<<1, 1024, 0, stream>>>(bsums, NB);
    scan_write_kernel<<<NB, 256, 0, stream>>>(counts, bsums, offsets, dinv, N);
    gemm_kernel<<<1024, 256, 0, stream>>>(x, W, h, N);
    reorder_kernel<<<(E + 255) / 256, 256, 0, stream>>>(ei, flag, offsets, srcs, E);
    gather_kernel<<<(N + 3) / 4, 256, 0, stream>>>(h, offsets, srcs, dinv, b, out, N);
}

// Round 3
// 242.576 us; speedup vs baseline: 1.5942x; 1.2340x over previous
//
#include <hip/hip_runtime.h>

#define DIM 64
#define BIN_SHIFT 7                  // 128 nodes per bin
#define NODES_PER_BIN 128
#define MAX_BINS 1024                // ceil(100000/128)=782 <= 1024
#define MAX_BIN_EDGES 4096           // avg ~1280, 5-sigma ~1460; 4096 is very safe
#define CHUNK_EDGES 4096             // edges per bin_scatter block

// ---------------- ws layout (256-aligned) ----------------
// flag(int) | gbhist[1024] | gbase[1024] | gcur[1024] | dinv[N] f32
// | pairs[E] int2 | h[N*64] f32    (~34 MB)

__device__ __forceinline__ void load_edge(const void* __restrict__ ei, int is64,
                                          int i, int E, int& s, int& d) {
    if (is64) {
        s = (int)((const long long*)ei)[i];
        d = (int)((const long long*)ei)[(long long)i + E];
    } else {
        s = ((const int*)ei)[i];
        d = ((const int*)ei)[i + E];
    }
}

__device__ __forceinline__ int load_dst(const void* __restrict__ ei, int is64, int i, int E) {
    return is64 ? (int)((const long long*)ei)[(long long)i + E]
                : ((const int*)ei)[i + E];
}

// Detect whether edge_index buffer is int64 (odd int32 words all zero) or int32.
__global__ void detect_idx64_kernel(const int* __restrict__ ei32, int* __restrict__ flag) {
    __shared__ int any_nz;
    if (threadIdx.x == 0) any_nz = 0;
    __syncthreads();
    int v = ei32[2 * threadIdx.x + 1];
    if (v != 0) atomicOr(&any_nz, 1);
    __syncthreads();
    if (threadIdx.x == 0) *flag = (any_nz == 0) ? 1 : 0;
}

__global__ void zero_bins_kernel(int* __restrict__ gbhist) {
    gbhist[blockIdx.x * blockDim.x + threadIdx.x] = 0;
}

// Pass A: global per-bin histogram, LDS-aggregated.
__global__ __launch_bounds__(256) void bin_hist_kernel(const void* __restrict__ ei,
                                                       const int* __restrict__ flagp,
                                                       int* __restrict__ gbhist,
                                                       int E, int nbins) {
    __shared__ int h[MAX_BINS];
    int tid = threadIdx.x;
    for (int i = tid; i < nbins; i += 256) h[i] = 0;
    __syncthreads();
    int is64 = *flagp;
    int stride = gridDim.x * blockDim.x;
    for (int i = blockIdx.x * blockDim.x + tid; i < E; i += stride) {
        int d = load_dst(ei, is64, i, E);
        atomicAdd(&h[d >> BIN_SHIFT], 1);
    }
    __syncthreads();
    for (int i = tid; i < nbins; i += 256) {
        int c = h[i];
        if (c) atomicAdd(&gbhist[i], c);
    }
}

// Pass A2: exclusive scan of bin counts -> gbase; gcur = gbase (mutable cursors).
__global__ __launch_bounds__(1024) void bin_scan_kernel(const int* __restrict__ gbhist,
                                                        int* __restrict__ gbase,
                                                        int* __restrict__ gcur, int nbins) {
    __shared__ int tmp[1024];
    int t = threadIdx.x;
    int v = (t < nbins) ? gbhist[t] : 0;
    tmp[t] = v; __syncthreads();
    for (int off = 1; off < 1024; off <<= 1) {
        int u = (t >= off) ? tmp[t - off] : 0;
        __syncthreads();
        tmp[t] += u;
        __syncthreads();
    }
    if (t < nbins) {
        int e = tmp[t] - v;
        gbase[t] = e;
        gcur[t] = e;
    }
}

// Pass B: scatter (src,dst) pairs into bin-contiguous storage.
// Per-block LDS aggregation -> one global atomicAdd per (block,bin) -> runs of
// consecutive 8B writes (good sector utilization).
__global__ __launch_bounds__(256) void bin_scatter_kernel(const void* __restrict__ ei,
                                                          const int* __restrict__ flagp,
                                                          int* __restrict__ gcur,
                                                          int2* __restrict__ pairs,
                                                          int E, int nbins) {
    __shared__ int h1[MAX_BINS];
    __shared__ int base[MAX_BINS];
    int tid = threadIdx.x;
    int is64 = *flagp;
    int chunk = blockIdx.x * CHUNK_EDGES;

    for (int i = tid; i < nbins; i += 256) h1[i] = 0;
    __syncthreads();
#pragma unroll
    for (int k = 0; k < CHUNK_EDGES / 256; ++k) {
        int i = chunk + k * 256 + tid;
        if (i < E) {
            int d = load_dst(ei, is64, i, E);
            atomicAdd(&h1[d >> BIN_SHIFT], 1);
        }
    }
    __syncthreads();
    for (int i = tid; i < nbins; i += 256) {
        int c = h1[i];
        base[i] = c ? atomicAdd(&gcur[i], c) : 0;
        h1[i] = 0;
    }
    __syncthreads();
#pragma unroll
    for (int k = 0; k < CHUNK_EDGES / 256; ++k) {
        int i = chunk + k * 256 + tid;
        if (i < E) {
            int s, d;
            load_edge(ei, is64, i, E, s, d);
            int bin = d >> BIN_SHIFT;
            int r = atomicAdd(&h1[bin], 1);
            pairs[base[bin] + r] = make_int2(s, d);
        }
    }
}

// Pass D: per-bin exact node degrees -> dinv. (All edges with dst=node live in
// node's bin, so the bin-local histogram IS the exact degree.)
__global__ __launch_bounds__(256) void degree_kernel(const int2* __restrict__ pairs,
                                                     const int* __restrict__ gbase,
                                                     const int* __restrict__ gcur,
                                                     float* __restrict__ dinv, int N) {
    __shared__ int deg[NODES_PER_BIN];
    int b = blockIdx.x;
    int tid = threadIdx.x;
    int start = gbase[b], end = gcur[b];
    int node0 = b << BIN_SHIFT;
    int nn = min(NODES_PER_BIN, N - node0);
    if (tid < NODES_PER_BIN) deg[tid] = 0;
    __syncthreads();
    for (int i = start + tid; i < end; i += 256)
        atomicAdd(&deg[pairs[i].y - node0], 1);
    __syncthreads();
    if (tid < nn) dinv[node0 + tid] = rsqrtf((float)(deg[tid] + 1));  // +1 self-loop
}

// h = x @ W^T.  Wave-per-row, lane-per-col.
__global__ __launch_bounds__(256) void gemm_kernel(const float* __restrict__ x,
                                                   const float* __restrict__ W,
                                                   float* __restrict__ h, int N) {
    __shared__ float Wt[64 * 64];        // k-major
    int tid = threadIdx.x;
    for (int i = tid; i < 64 * 64; i += 256) Wt[i] = W[((i & 63) << 6) | (i >> 6)];
    __syncthreads();
    int lane = tid & 63;
    float wreg[64];
#pragma unroll
    for (int k = 0; k < 64; ++k) wreg[k] = Wt[k * 64 + lane];

    int wave = (blockIdx.x * blockDim.x + threadIdx.x) >> 6;
    int nwaves = (gridDim.x * blockDim.x) >> 6;
    for (int r = wave; r < N; r += nwaves) {
        int rs = __builtin_amdgcn_readfirstlane(r);
        const float4* xr = (const float4*)(x + (long long)rs * DIM);
        float acc = 0.0f;
#pragma unroll
        for (int kk = 0; kk < 16; ++kk) {
            float4 xv = xr[kk];
            acc = fmaf(xv.x, wreg[4 * kk + 0], acc);
            acc = fmaf(xv.y, wreg[4 * kk + 1], acc);
            acc = fmaf(xv.z, wreg[4 * kk + 2], acc);
            acc = fmaf(xv.w, wreg[4 * kk + 3], acc);
        }
        h[(long long)rs * DIM + lane] = acc;
    }
}

// Pass C: per-bin gather. Build LDS CSR (counting sort over 128 local nodes),
// then wave-per-node segmented gather. Self-loop + bias fused.
__global__ __launch_bounds__(256) void bin_gather_kernel(const int2* __restrict__ pairs,
                                                         const int* __restrict__ gbase,
                                                         const int* __restrict__ gcur,
                                                         const float* __restrict__ h,
                                                         const float* __restrict__ dinv,
                                                         const float* __restrict__ bias,
                                                         float* __restrict__ out, int N) {
    __shared__ int csr[MAX_BIN_EDGES];
    __shared__ int sdeg[NODES_PER_BIN];
    __shared__ int sofs[NODES_PER_BIN];
    __shared__ int scur[NODES_PER_BIN];
    int b = blockIdx.x;
    int tid = threadIdx.x;
    int start = gbase[b], end = gcur[b];
    int cnt = end - start;
    int node0 = b << BIN_SHIFT;
    int nn = min(NODES_PER_BIN, N - node0);

    if (tid < NODES_PER_BIN) sdeg[tid] = 0;
    __syncthreads();
    for (int i = tid; i < cnt; i += 256)
        atomicAdd(&sdeg[pairs[start + i].y - node0], 1);
    __syncthreads();
    // exclusive scan of 128 degrees (Hillis-Steele)
    if (tid < NODES_PER_BIN) sofs[tid] = sdeg[tid];
    __syncthreads();
    for (int off = 1; off < NODES_PER_BIN; off <<= 1) {
        int v = (tid >= off && tid < NODES_PER_BIN) ? sofs[tid - off] : 0;
        __syncthreads();
        if (tid < NODES_PER_BIN) sofs[tid] += v;
        __syncthreads();
    }
    if (tid < NODES_PER_BIN) {
        int e = sofs[tid] - sdeg[tid];
        sofs[tid] = e;
        scur[tid] = e;
    }
    __syncthreads();
    for (int i = tid; i < cnt; i += 256) {
        int2 p = pairs[start + i];
        int r = atomicAdd(&scur[p.y - node0], 1);
        csr[r] = p.x;
    }
    __syncthreads();

    int wave = tid >> 6;
    int lane = tid & 63;
    float bl = bias[lane];
    for (int ld = wave; ld < nn; ld += 4) {
        int g = node0 + ld;
        float dn = dinv[g];
        float acc = h[(long long)g * DIM + lane] * dn * dn;   // self-loop
        int j = sofs[ld];
        int e = j + sdeg[ld];
        for (; j + 1 < e; j += 2) {
            int s0 = csr[j], s1 = csr[j + 1];
            float w0 = dinv[s0] * dn, w1 = dinv[s1] * dn;
            float v0 = h[(long long)s0 * DIM + lane];
            float v1 = h[(long long)s1 * DIM + lane];
            acc = fmaf(v0, w0, acc);
            acc = fmaf(v1, w1, acc);
        }
        if (j < e) {
            int s0 = csr[j];
            acc = fmaf(h[(long long)s0 * DIM + lane], dinv[s0] * dn, acc);
        }
        out[(long long)g * DIM + lane] = acc + bl;
    }
}

extern "C" void kernel_launch(void* const* d_in, const int* in_sizes, int n_in,
                              void* d_out, int out_size, void* d_ws, size_t ws_size,
                              hipStream_t stream) {
    const float* x = (const float*)d_in[0];
    const void* ei = d_in[1];
    const float* W = (const float*)d_in[2];
    const float* b = (const float*)d_in[3];
    float* out = (float*)d_out;

    int N = in_sizes[0] / DIM;   // 100000
    int E = in_sizes[1] / 2;     // 1000000
    int nbins = (N + NODES_PER_BIN - 1) >> BIN_SHIFT;   // 782

    char* ws = (char*)d_ws;
    auto align256 = [](size_t v) { return (v + 255) & ~(size_t)255; };
    size_t off = 0;
    int* flag = (int*)(ws + off);        off = align256(off + 4);
    int* gbhist = (int*)(ws + off);      off = align256(off + MAX_BINS * 4);
    int* gbase = (int*)(ws + off);       off = align256(off + MAX_BINS * 4);
    int* gcur = (int*)(ws + off);        off = align256(off + MAX_BINS * 4);
    float* dinv = (float*)(ws + off);    off = align256(off + (size_t)N * 4);
    int2* pairs = (int2*)(ws + off);     off = align256(off + (size_t)E * 8);
    float* h = (float*)(ws + off);       off = align256(off + (size_t)N * DIM * 4);

    int nchunks = (E + CHUNK_EDGES - 1) / CHUNK_EDGES;   // 245

    detect_idx64_kernel<<<1, 256, 0, stream>>>((const int*)ei, flag);
    zero_bins_kernel<<<MAX_BINS / 256, 256, 0, stream>>>(gbhist);
    bin_hist_kernel<<<512, 256, 0, stream>>>(ei, flag, gbhist, E, nbins);
    bin_scan_kernel<<<1, 1024, 0, stream>>>(gbhist, gbase, gcur, nbins);
    bin_scatter_kernel<<<nchunks, 256, 0, stream>>>(ei, flag, gcur, pairs, E, nbins);
    degree_kernel<<<nbins, 256, 0, stream>>>(pairs, gbase, gcur, dinv, N);
    gemm_kernel<<<1024, 256, 0, stream>>>(x, W, h, N);
    bin_gather_kernel<<<nbins, 256, 0, stream>>>(pairs, gbase, gcur, h, dinv, b, out, N);
}

// Round 4
// 181.548 us; speedup vs baseline: 2.1301x; 1.3362x over previous
//
#include <hip/hip_runtime.h>

#define DIM 64
#define BIN_SHIFT 7                  // 128 nodes per bin
#define NODES_PER_BIN 128
#define MAX_BINS 1024                // ceil(100000/128)=782 <= 1024
#define BIN_CAP 2048                 // mean 1279, sigma ~36 -> 21-sigma margin
#define CHUNK_EDGES 4096             // edges per bin_scatter block

// ws layout (256-aligned):
// flag | gcur[1024] | dinv[N] | deg16[N] | ofs[N] | pairs[nbins*BIN_CAP] | h[N*64]

__device__ __forceinline__ void load_edge(const void* __restrict__ ei, int is64,
                                          int i, int E, int& s, int& d) {
    if (is64) {
        s = (int)((const long long*)ei)[i];
        d = (int)((const long long*)ei)[(long long)i + E];
    } else {
        s = ((const int*)ei)[i];
        d = ((const int*)ei)[i + E];
    }
}

// init: detect int64-vs-int32 edge buffer + zero bin cursors. One block.
__global__ __launch_bounds__(256) void init_kernel(const int* __restrict__ ei32,
                                                   int* __restrict__ flag,
                                                   int* __restrict__ gcur) {
    __shared__ int any_nz;
    int tid = threadIdx.x;
    if (tid == 0) any_nz = 0;
    __syncthreads();
    int v = ei32[2 * tid + 1];     // odd int32 words: all-zero iff nonneg int64 data
    if (v != 0) atomicOr(&any_nz, 1);
    for (int i = tid; i < MAX_BINS; i += 256) gcur[i] = 0;
    __syncthreads();
    if (tid == 0) *flag = (any_nz == 0) ? 1 : 0;
}

// Pass 1: scatter packed (src<<7 | dst&127) into fixed-capacity dst-bins.
// Block-level LDS histogram -> one global reservation atomic per (block,bin).
__global__ __launch_bounds__(256) void bin_scatter_kernel(const void* __restrict__ ei,
                                                          const int* __restrict__ flagp,
                                                          int* __restrict__ gcur,
                                                          int* __restrict__ pairs,
                                                          int E, int nbins) {
    __shared__ int h1[MAX_BINS];
    __shared__ int base[MAX_BINS];
    int tid = threadIdx.x;
    int is64 = *flagp;
    int chunk = blockIdx.x * CHUNK_EDGES;

    for (int i = tid; i < nbins; i += 256) h1[i] = 0;
    __syncthreads();
#pragma unroll
    for (int k = 0; k < CHUNK_EDGES / 256; ++k) {
        int i = chunk + k * 256 + tid;
        if (i < E) {
            int d = is64 ? (int)((const long long*)ei)[(long long)i + E]
                         : ((const int*)ei)[i + E];
            atomicAdd(&h1[d >> BIN_SHIFT], 1);
        }
    }
    __syncthreads();
    for (int i = tid; i < nbins; i += 256) {
        int c = h1[i];
        base[i] = c ? (i * BIN_CAP + atomicAdd(&gcur[i], c)) : 0;
        h1[i] = 0;
    }
    __syncthreads();
#pragma unroll
    for (int k = 0; k < CHUNK_EDGES / 256; ++k) {
        int i = chunk + k * 256 + tid;
        if (i < E) {
            int s, d;
            load_edge(ei, is64, i, E, s, d);
            int bin = d >> BIN_SHIFT;
            int r = atomicAdd(&h1[bin], 1);
            int pos = base[bin] + r;
            if (pos < (bin + 1) * BIN_CAP)          // overflow guard (never expected)
                pairs[pos] = (s << BIN_SHIFT) | (d & (NODES_PER_BIN - 1));
        }
    }
}

// Pass 2: per-bin CSR build. LDS counting sort over 128 local nodes; writes the
// sorted src ids back IN PLACE over the bin region; emits ofs/deg16/dinv.
__global__ __launch_bounds__(256) void bin_csr_kernel(int* __restrict__ pairs,
                                                      const int* __restrict__ gcur,
                                                      int* __restrict__ ofs,
                                                      unsigned short* __restrict__ deg16,
                                                      float* __restrict__ dinv, int N) {
    __shared__ int csr[BIN_CAP];
    __shared__ int sdeg[NODES_PER_BIN];
    __shared__ int sofs[NODES_PER_BIN];
    __shared__ int scur[NODES_PER_BIN];
    int b = blockIdx.x;
    int tid = threadIdx.x;
    int base = b * BIN_CAP;
    int cnt = min(gcur[b], BIN_CAP);
    int node0 = b << BIN_SHIFT;
    int nn = min(NODES_PER_BIN, N - node0);

    if (tid < NODES_PER_BIN) sdeg[tid] = 0;
    __syncthreads();
    for (int i = tid; i < cnt; i += 256)
        atomicAdd(&sdeg[pairs[base + i] & (NODES_PER_BIN - 1)], 1);
    __syncthreads();
    if (tid < NODES_PER_BIN) sofs[tid] = sdeg[tid];
    __syncthreads();
    for (int off = 1; off < NODES_PER_BIN; off <<= 1) {
        int v = (tid >= off && tid < NODES_PER_BIN) ? sofs[tid - off] : 0;
        __syncthreads();
        if (tid < NODES_PER_BIN) sofs[tid] += v;
        __syncthreads();
    }
    if (tid < NODES_PER_BIN) {
        int e = sofs[tid] - sdeg[tid];
        sofs[tid] = e;
        scur[tid] = e;
        if (tid < nn) {
            int g = node0 + tid;
            ofs[g] = base + e;
            deg16[g] = (unsigned short)sdeg[tid];
            dinv[g] = rsqrtf((float)(sdeg[tid] + 1));   // +1 self-loop
        }
    }
    __syncthreads();
    for (int i = tid; i < cnt; i += 256) {
        int p = pairs[base + i];
        int r = atomicAdd(&scur[p & (NODES_PER_BIN - 1)], 1);
        csr[r] = p >> BIN_SHIFT;                         // src id
    }
    __syncthreads();
    for (int i = tid; i < cnt; i += 256) pairs[base + i] = csr[i];
}

// h[r] = (x[r] @ W^T) * dinv[r]  — wave-per-row, lane-per-col, W in 64 regs.
__global__ __launch_bounds__(256) void gemm_kernel(const float* __restrict__ x,
                                                   const float* __restrict__ W,
                                                   const float* __restrict__ dinv,
                                                   float* __restrict__ h, int N) {
    __shared__ float Wt[64 * 64];        // k-major
    int tid = threadIdx.x;
    for (int i = tid; i < 64 * 64; i += 256) Wt[i] = W[((i & 63) << 6) | (i >> 6)];
    __syncthreads();
    int lane = tid & 63;
    float wreg[64];
#pragma unroll
    for (int k = 0; k < 64; ++k) wreg[k] = Wt[k * 64 + lane];

    int wave = (blockIdx.x * blockDim.x + threadIdx.x) >> 6;
    int nwaves = (gridDim.x * blockDim.x) >> 6;
    for (int r = wave; r < N; r += nwaves) {
        int rs = __builtin_amdgcn_readfirstlane(r);
        const float4* xr = (const float4*)(x + (long long)rs * DIM);
        float acc = 0.0f;
#pragma unroll
        for (int kk = 0; kk < 16; ++kk) {
            float4 xv = xr[kk];
            acc = fmaf(xv.x, wreg[4 * kk + 0], acc);
            acc = fmaf(xv.y, wreg[4 * kk + 1], acc);
            acc = fmaf(xv.z, wreg[4 * kk + 2], acc);
            acc = fmaf(xv.w, wreg[4 * kk + 3], acc);
        }
        h[(long long)rs * DIM + lane] = acc * dinv[rs];  // pre-scale by dinv[src]
    }
}

// Pass 3: wave-per-node gather over the global CSR. h is pre-scaled by dinv[s]:
// out[d] = dinv[d] * (h_s[d] + sum_s h_s[s]) + b.
__global__ __launch_bounds__(256) void gather_kernel(const float* __restrict__ h,
                                                     const int* __restrict__ ofs,
                                                     const unsigned short* __restrict__ deg16,
                                                     const int* __restrict__ srcs,
                                                     const float* __restrict__ dinv,
                                                     const float* __restrict__ bias,
                                                     float* __restrict__ out, int N) {
    int node = __builtin_amdgcn_readfirstlane((blockIdx.x * blockDim.x + threadIdx.x) >> 6);
    if (node >= N) return;
    int lane = threadIdx.x & 63;
    int st = ofs[node];
    int dg = deg16[node];
    float dn = dinv[node];
    float a0 = h[(long long)node * DIM + lane];   // self-loop (pre-scaled by dinv[node])
    float a1 = 0.0f;
    int j = 0;
    for (; j + 3 < dg; j += 4) {
        int s0 = srcs[st + j + 0];
        int s1 = srcs[st + j + 1];
        int s2 = srcs[st + j + 2];
        int s3 = srcs[st + j + 3];
        float v0 = h[(long long)s0 * DIM + lane];
        float v1 = h[(long long)s1 * DIM + lane];
        float v2 = h[(long long)s2 * DIM + lane];
        float v3 = h[(long long)s3 * DIM + lane];
        a0 += v0 + v2;
        a1 += v1 + v3;
    }
    for (; j < dg; ++j)
        a0 += h[(long long)srcs[st + j] * DIM + lane];
    out[(long long)node * DIM + lane] = (a0 + a1) * dn + bias[lane];
}

extern "C" void kernel_launch(void* const* d_in, const int* in_sizes, int n_in,
                              void* d_out, int out_size, void* d_ws, size_t ws_size,
                              hipStream_t stream) {
    const float* x = (const float*)d_in[0];
    const void* ei = d_in[1];
    const float* W = (const float*)d_in[2];
    const float* b = (const float*)d_in[3];
    float* out = (float*)d_out;

    int N = in_sizes[0] / DIM;   // 100000
    int E = in_sizes[1] / 2;     // 1000000
    int nbins = (N + NODES_PER_BIN - 1) >> BIN_SHIFT;   // 782

    char* ws = (char*)d_ws;
    auto align256 = [](size_t v) { return (v + 255) & ~(size_t)255; };
    size_t off = 0;
    int* flag = (int*)(ws + off);              off = align256(off + 4);
    int* gcur = (int*)(ws + off);              off = align256(off + MAX_BINS * 4);
    float* dinv = (float*)(ws + off);          off = align256(off + (size_t)N * 4);
    unsigned short* deg16 = (unsigned short*)(ws + off); off = align256(off + (size_t)N * 2);
    int* ofs = (int*)(ws + off);               off = align256(off + (size_t)N * 4);
    int* pairs = (int*)(ws + off);             off = align256(off + (size_t)nbins * BIN_CAP * 4);
    float* h = (float*)(ws + off);             off = align256(off + (size_t)N * DIM * 4);

    int nchunks = (E + CHUNK_EDGES - 1) / CHUNK_EDGES;   // 245
    int gblocks = (N + 3) / 4;                           // wave-per-node, 4 waves/block

    init_kernel<<<1, 256, 0, stream>>>((const int*)ei, flag, gcur);
    bin_scatter_kernel<<<nchunks, 256, 0, stream>>>(ei, flag, gcur, pairs, E, nbins);
    bin_csr_kernel<<<nbins, 256, 0, stream>>>(pairs, gcur, ofs, deg16, dinv, N);
    gemm_kernel<<<1024, 256, 0, stream>>>(x, W, dinv, h, N);
    gather_kernel<<<gblocks, 256, 0, stream>>>(h, ofs, deg16, pairs, dinv, b, out, N);
}